// Round 2
// 331.130 us; speedup vs baseline: 1.0322x; 1.0322x over previous
//
#include <hip/hip_runtime.h>
#include <math.h>

typedef unsigned char  uchar_t;
typedef unsigned int   uint32;
typedef __attribute__((ext_vector_type(4)))  int   i32x4;
typedef __attribute__((ext_vector_type(8)))  int   i32x8;
typedef __attribute__((ext_vector_type(16))) float f32x16;

#define EMB     512
#define NROWS   8192
#define NITEMS  4096
#define NSPLIT  16
#define CPS     512
#define CTILE   128
#define QTILE   128
#define NSTEPS  32
#define LDEPTH  8
#define KEEP    8
#define NRESC   16

// Proven form only: LDS dest = base + lane*16, imm offset MUST stay 0
// (on CDNA the instruction immediate also offsets the LDS write address).
#define GLOAD_LDS(gp, lp) __builtin_amdgcn_global_load_lds( \
    (const __attribute__((address_space(1))) void*)(gp),    \
    (__attribute__((address_space(3))) void*)(lp), 16, 0, 0)

__device__ inline uint32 packkey(float v, int idx) {
    uint32 u = __float_as_uint(v);
    uint32 s = u ^ ((u & 0x80000000u) ? 0xFFFFFFFFu : 0x80000000u);
    return (s & 0xFFFFE000u) | ((uint32)idx ^ 0x1FFFu);
}

// ---------------- Phase A: fp64 norms + normalized fp8(e4m3, x16) plane ----------------
__global__ void prep_kernel(const float* __restrict__ E,
                            uchar_t* __restrict__ Xq, double* __restrict__ invd) {
    const int row  = blockIdx.x * 4 + (threadIdx.x >> 6);
    const int lane = threadIdx.x & 63;
    const float4* p = (const float4*)(E + (size_t)row * EMB);
    float4 f0 = p[lane];
    float4 f1 = p[lane + 64];
    double s = (double)f0.x*f0.x + (double)f0.y*f0.y + (double)f0.z*f0.z + (double)f0.w*f0.w
             + (double)f1.x*f1.x + (double)f1.y*f1.y + (double)f1.z*f1.z + (double)f1.w*f1.w;
#pragma unroll
    for (int m = 32; m > 0; m >>= 1) s += __shfl_xor(s, m);
    const double inv = 1.0 / sqrt(s);
    if (lane == 0) invd[row] = inv;
    const float sc = (float)inv * 16.0f;
    int w0 = 0, w1 = 0;
    w0 = __builtin_amdgcn_cvt_pk_fp8_f32(f0.x * sc, f0.y * sc, w0, false);
    w0 = __builtin_amdgcn_cvt_pk_fp8_f32(f0.z * sc, f0.w * sc, w0, true);
    w1 = __builtin_amdgcn_cvt_pk_fp8_f32(f1.x * sc, f1.y * sc, w1, false);
    w1 = __builtin_amdgcn_cvt_pk_fp8_f32(f1.z * sc, f1.w * sc, w1, true);
    ((int2*)(Xq + (size_t)row * EMB))[lane] = make_int2(w0, w1);
}

// ---------------- Phase B: dbuf MX-fp8 32x32x64 MFMA, 128x128 tile, 4 blocks/CU ----------------
// R2: keep R1's occupancy lever (CTILE=128, NSPLIT=16, grid=1024=4/CU, 32KB LDS,
// launch_bounds(256,4), KEEP=8); REVERT imm-offset global_load_lds (inst offset
// also shifts the LDS dest -> tile corruption) and biased packkey (back to
// proven sign-flip form).
__global__ __launch_bounds__(256, 4) void sim_topk_mfma(
    const uchar_t* __restrict__ Xq, uint32* __restrict__ keys_out) {

    __shared__ union {
        struct { uchar_t A[2][8192]; uchar_t B[2][8192]; } s;  // 32 KB dbuf staging
        struct { uint32 mk[128][37]; } m;                       // 18.9 KB merge
    } sh;

    const int t     = threadIdx.x;
    const int lane  = t & 63;
    const int wave  = t >> 6;
    const int wm    = wave >> 1;
    const int wn    = wave & 1;
    const int rb    = blockIdx.x >> 4;
    const int split = blockIdx.x & 15;
    const int qbase = rb * QTILE;
    const int l31   = lane & 31;
    const int l5    = lane >> 5;

    // 16 DMAs/step (A:8, B:8) -> 4 per wave, explicit pointer per chunk (offset=0).
    // waves 0,1 stage A (candidate rows), waves 2,3 stage B (query rows).
    // chunk j holds rows (j>>1)*32 + l31, k-bytes ((j&1)*2 + l5)*16 .. +16
    const bool isA   = (wave < 2);
    const int  jb4   = (wave & 1) * 4;
    const int  mbase = isA ? split * CPS : qbase;
    const uchar_t* base =
        Xq + (size_t)(mbase + (jb4 >> 1) * 32 + l31) * EMB + (l5 << 4);
    const uchar_t* cur[4];
    cur[0] = base;                           // chunk jb4   : k 0..31
    cur[1] = base + 32;                      // chunk jb4+1 : k 32..63
    cur[2] = base + (size_t)32 * EMB;        // chunk jb4+2 : rows +32, k 0..31
    cur[3] = base + (size_t)32 * EMB + 32;   // chunk jb4+3 : rows +32, k 32..63

    auto stage = [&](int buf) {
        uchar_t* bp = (isA ? sh.s.A[buf] : sh.s.B[buf]) + jb4 * 1024;
        GLOAD_LDS(cur[0], bp);
        GLOAD_LDS(cur[1], bp + 1024);
        GLOAD_LDS(cur[2], bp + 2048);
        GLOAD_LDS(cur[3], bp + 3072);
    };

    uint32 tv[2][LDEPTH];
#pragma unroll
    for (int fc = 0; fc < 2; ++fc)
#pragma unroll
        for (int d = 0; d < LDEPTH; ++d) tv[fc][d] = 0u;

    f32x16 acc[2][2];
#pragma unroll
    for (int fr = 0; fr < 2; ++fr)
#pragma unroll
        for (int fc = 0; fc < 2; ++fc)
#pragma unroll
            for (int q = 0; q < 16; ++q) acc[fr][fc][q] = 0.f;

    stage(0);   // prologue: step 0

    const int fo = (l5 << 10) + (l31 << 4);

    union U8 { i32x8 v8; struct { i32x4 lo; i32x4 hi; } h; };

#pragma unroll 1
    for (int s = 0; s < NSTEPS; ++s) {
        const int buf = s & 1;

        __syncthreads();   // drains this step's DMA (issued one compute-phase ago)

        if (s + 1 < NSTEPS) {
            const bool newct = ((s + 1) & 7) == 0;
            const long d = isA ? (newct ? (long)CTILE * EMB - 7 * 64 : 64)
                               : (newct ? -(long)(7 * 64) : 64);
#pragma unroll
            for (int c = 0; c < 4; ++c) cur[c] += d;
            stage((s + 1) & 1);
        }

        // LDS -> fragments: keep only a0,a1,b live (24 VGPRs transient)
        U8 a0, a1, b;
        {
            const int ca = (wm * 2) * 2048;
            a0.h.lo = *(const i32x4*)&sh.s.A[buf][ca + fo];
            a0.h.hi = *(const i32x4*)&sh.s.A[buf][ca + 512 + fo];
            a1.h.lo = *(const i32x4*)&sh.s.A[buf][ca + 2048 + fo];
            a1.h.hi = *(const i32x4*)&sh.s.A[buf][ca + 2048 + 512 + fo];
        }
        {
            const int cb = (wn * 2) * 2048;
            b.h.lo = *(const i32x4*)&sh.s.B[buf][cb + fo];
            b.h.hi = *(const i32x4*)&sh.s.B[buf][cb + 512 + fo];
        }
        acc[0][0] = __builtin_amdgcn_mfma_scale_f32_32x32x64_f8f6f4(
            a0.v8, b.v8, acc[0][0], 0, 0, 0, 0x7F7F7F7F, 0, 0x7F7F7F7F);
        acc[1][0] = __builtin_amdgcn_mfma_scale_f32_32x32x64_f8f6f4(
            a1.v8, b.v8, acc[1][0], 0, 0, 0, 0x7F7F7F7F, 0, 0x7F7F7F7F);
        {
            const int cb = (wn * 2 + 1) * 2048;
            b.h.lo = *(const i32x4*)&sh.s.B[buf][cb + fo];
            b.h.hi = *(const i32x4*)&sh.s.B[buf][cb + 512 + fo];
        }
        acc[0][1] = __builtin_amdgcn_mfma_scale_f32_32x32x64_f8f6f4(
            a0.v8, b.v8, acc[0][1], 0, 0, 0, 0x7F7F7F7F, 0, 0x7F7F7F7F);
        acc[1][1] = __builtin_amdgcn_mfma_scale_f32_32x32x64_f8f6f4(
            a1.v8, b.v8, acc[1][1], 0, 0, 0, 0x7F7F7F7F, 0, 0x7F7F7F7F);

        if ((s & 7) == 7) {
            // ---- register-only epilogue: packed-key insert into per-lane top-8 ----
            const int cand0 = split * CPS + (s >> 3) * CTILE;
#pragma unroll
            for (int fc = 0; fc < 2; ++fc) {
#pragma unroll
                for (int fr = 0; fr < 2; ++fr) {
                    float t0 = fmaxf(fmaxf(acc[fr][fc][0],  acc[fr][fc][1]),  acc[fr][fc][2]);
                    float t1 = fmaxf(fmaxf(acc[fr][fc][3],  acc[fr][fc][4]),  acc[fr][fc][5]);
                    float t2 = fmaxf(fmaxf(acc[fr][fc][6],  acc[fr][fc][7]),  acc[fr][fc][8]);
                    float t3 = fmaxf(fmaxf(acc[fr][fc][9],  acc[fr][fc][10]), acc[fr][fc][11]);
                    float t4 = fmaxf(fmaxf(acc[fr][fc][12], acc[fr][fc][13]), acc[fr][fc][14]);
                    float mx = fmaxf(fmaxf(fmaxf(t0, t1), t2),
                                     fmaxf(fmaxf(t3, t4), acc[fr][fc][15]));
                    if (packkey(mx, 0) > tv[fc][LDEPTH - 1]) {
                        const int jb = cand0 + wm * 64 + fr * 32 + (l5 << 2);
#pragma unroll
                        for (int reg = 0; reg < 16; ++reg) {
                            const int ci = jb + (reg & 3) + ((reg >> 2) << 3);
                            uint32 key = packkey(acc[fr][fc][reg], ci);
                            if (key > tv[fc][LDEPTH - 1]) {
                                uint32 c2 = key;
#pragma unroll
                                for (int d = 0; d < LDEPTH; ++d) {
                                    const uint32 a  = tv[fc][d];
                                    const uint32 hi = a > c2 ? a : c2;
                                    c2              = a > c2 ? c2 : a;
                                    tv[fc][d] = hi;
                                }
                            }
                        }
                    }
#pragma unroll
                    for (int q = 0; q < 16; ++q) acc[fr][fc][q] = 0.f;
                }
            }
        }
    }

    // ---- merge 4 lane-lists per query, emit sorted top-8 keys ----
    __syncthreads();
#pragma unroll
    for (int fc = 0; fc < 2; ++fc) {
        const int col = wn * 64 + fc * 32 + l31;
        const int sl  = wm * 2 + l5;
#pragma unroll
        for (int d = 0; d < LDEPTH; ++d) sh.m.mk[col][sl * 9 + d] = tv[fc][d];
        sh.m.mk[col][sl * 9 + 8] = 0u;   // sentinel: 4-pointer merge needs no bounds check
    }
    __syncthreads();
    if (t < 128) {
        int p[4] = {0, 0, 0, 0};
        const size_t base2 = ((size_t)(qbase + t) * NSPLIT + split) * KEEP;
#pragma unroll 1
        for (int sel = 0; sel < KEEP; ++sel) {
            uint32 bk = 0; int bl = 0;
#pragma unroll
            for (int l = 0; l < 4; ++l) {
                uint32 k = sh.m.mk[t][l * 9 + p[l]];
                if (k > bk) { bk = k; bl = l; }
            }
            p[bl]++;
            keys_out[base2 + sel] = bk;
        }
    }
}

// ---------------- Phase C: one row per block — rank-select top-16 + fp64 rescue ----------------
__global__ __launch_bounds__(256) void rescue_kernel(
    const float* __restrict__ E, const double* __restrict__ invd,
    const uint32* __restrict__ keys,
    const int* __restrict__ n_users, const int* __restrict__ n_entitys,
    const int* __restrict__ interactions, float* __restrict__ out) {

    __shared__ uint32 skeys[128];
    __shared__ float4 sq[128];
    __shared__ int    scand[NRESC];
    __shared__ double sd[NRESC];
    __shared__ int    sci[NRESC];
    __shared__ float  smemb[NRESC];
    __shared__ double contrib[8];

    const int t   = threadIdx.x;
    const int row = blockIdx.x;

    if (t < 128) {
        skeys[t] = keys[(size_t)row * 128 + t];
        sq[t]    = ((const float4*)(E + (size_t)row * EMB))[t];
    }
    if (t < NRESC) scand[t] = 0;      // poison-proof
    if (t < 8)     contrib[t] = 0.0;
    __syncthreads();

    if (t < 128) {
        const uint32 k = skeys[t];
        int r = 0;
#pragma unroll 16
        for (int j = 0; j < 128; ++j) {
            const uint32 kj = skeys[j];
            r += (kj > k) || (kj == k && j < t);
        }
        if (r < NRESC) scand[r] = (int)((k & 0x1FFFu) ^ 0x1FFFu);
    }
    __syncthreads();

    const int g    = t >> 4;
    const int l16  = t & 15;
    const int cand = scand[g] & (NROWS - 1);
    const float4* C = (const float4*)(E + (size_t)cand * EMB);
    double acc = 0.0;
#pragma unroll
    for (int j = 0; j < 8; ++j) {
        float4 c = C[l16 + 16 * j];
        float4 q = sq[l16 + 16 * j];
        acc += (double)q.x * c.x + (double)q.y * c.y
             + (double)q.z * c.z + (double)q.w * c.w;
    }
#pragma unroll
    for (int m = 8; m >= 1; m >>= 1) acc += __shfl_xor(acc, m, 16);

    const int ent = n_entitys[row];
    if (l16 == 0) { sd[g] = acc * invd[row] * invd[cand]; sci[g] = cand; }
    if (l16 == 1) {
        const int uid = n_users[cand];
        smemb[g] = (float)interactions[(size_t)uid * NITEMS + ent];
    }
    __syncthreads();

    if (t < NRESC) {
        const double v  = sd[t];
        const int    ci = sci[t];
        int r = 0;
#pragma unroll
        for (int j = 0; j < NRESC; ++j) {
            const double vj = sd[j];
            const int    cj = sci[j];
            r += (vj > v) || (vj == v && (cj < ci || (cj == ci && j < t)));
        }
        if (r < 6) contrib[r] = v * (double)smemb[t];
    }
    __syncthreads();
    if (t == 0) {
        const double sum = contrib[0] + contrib[1] + contrib[2]
                         + contrib[3] + contrib[4] + contrib[5];
        out[row] = (float)(sum * (1.0 / 6.0));
    }
}

extern "C" void kernel_launch(void* const* d_in, const int* in_sizes, int n_in,
                              void* d_out, int out_size, void* d_ws, size_t ws_size,
                              hipStream_t stream) {
    const float* E            = (const float*)d_in[0];
    const int*   n_users      = (const int*)d_in[1];
    const int*   n_entitys    = (const int*)d_in[2];
    const int*   interactions = (const int*)d_in[3];
    float*       out          = (float*)d_out;

    uchar_t* Xq   = (uchar_t*)d_ws;
    double*  invd = (double*)(Xq + (size_t)NROWS * EMB);
    uint32*  keys = (uint32*)(invd + NROWS);

    prep_kernel<<<NROWS / 4, 256, 0, stream>>>(E, Xq, invd);
    sim_topk_mfma<<<(NROWS / QTILE) * NSPLIT, 256, 0, stream>>>(Xq, keys);
    rescue_kernel<<<NROWS, 256, 0, stream>>>(E, invd, keys, n_users, n_entitys,
                                             interactions, out);
}